// Round 1
// baseline (1239.357 us; speedup 1.0000x reference)
//
#include <hip/hip_runtime.h>
#include <math.h>

#define EMBED 512
#define B2    256
#define MAXL  2048

// ---------------------------------------------------------------------------
// Kernel 1: w_eff[d] = sum_e W[e][d] * v[e]   (W is [out=512][in=512] row-major)
// grid: 16 blocks x 1024 threads. Block k covers e in [k*32, k*32+32).
// Thread = (d = tid&511, half = tid>>9): 16 e-values each, coalesced reads,
// one atomicAdd per thread into the zero-initialized w_eff.
// ---------------------------------------------------------------------------
__global__ __launch_bounds__(1024) void weff_kernel(const float* __restrict__ W,
                                                    const float* __restrict__ v,
                                                    float* __restrict__ weff) {
    int d    = threadIdx.x & (EMBED - 1);
    int half = threadIdx.x >> 9;             // 0 or 1
    int e0   = blockIdx.x * 32 + half * 16;
    float acc = 0.f;
#pragma unroll
    for (int i = 0; i < 16; ++i) {
        int e = e0 + i;
        acc += W[(size_t)e * EMBED + d] * v[e];
    }
    atomicAdd(&weff[d], acc);
}

// ---------------------------------------------------------------------------
// Kernel 2: energies[b,l] = dot(questions[b,l,:], w_eff)  for l < len[b]
//           energies[b,l] = -inf                          for l >= len[b]
// One wave (64 lanes) per token. Lane i loads 2 float4 (32B) of the token row
// (wave reads a contiguous 2KB chunk) and 2 float4 of w_eff (L1-resident).
// Masked tokens skip the 2KB read entirely (halves HBM traffic on average).
// ---------------------------------------------------------------------------
__global__ __launch_bounds__(256) void energy_kernel(const float* __restrict__ q,
                                                     const int*   __restrict__ lens,
                                                     const float* __restrict__ weff,
                                                     float*       __restrict__ energies) {
    int w    = (blockIdx.x * 256 + threadIdx.x) >> 6;   // global wave id == b*2048 + l
    int lane = threadIdx.x & 63;
    int b    = w >> 11;                                 // / 2048
    int l    = w & (MAXL - 1);
    int len  = lens[b];
    if (l >= len) {
        if (lane == 0) energies[w] = -INFINITY;
        return;
    }
    const float4* qp = (const float4*)(q + ((size_t)w << 9)) + lane * 2;
    float4 a0 = qp[0];
    float4 a1 = qp[1];
    const float4* wp = (const float4*)weff + lane * 2;
    float4 w0 = wp[0];
    float4 w1 = wp[1];
    float p = a0.x * w0.x + a0.y * w0.y + a0.z * w0.z + a0.w * w0.w
            + a1.x * w1.x + a1.y * w1.y + a1.z * w1.z + a1.w * w1.w;
#pragma unroll
    for (int off = 32; off > 0; off >>= 1) p += __shfl_down(p, off);
    if (lane == 0) energies[w] = p;
}

// ---------------------------------------------------------------------------
// Kernel 3: masked softmax along L per batch row. One block (256 thr) per row;
// 8 energies per thread held in registers; exp(-inf - m) = 0 emits the zeros
// for masked positions automatically.
// ---------------------------------------------------------------------------
__global__ __launch_bounds__(256) void softmax_kernel(const float* __restrict__ eng,
                                                      float*       __restrict__ out) {
    __shared__ float red[4];
    __shared__ float bc;
    int b = blockIdx.x;
    int t = threadIdx.x;
    const float4* ep = (const float4*)(eng + (size_t)b * MAXL);
    float4 c0 = ep[2 * t];
    float4 c1 = ep[2 * t + 1];
    float v8[8] = {c0.x, c0.y, c0.z, c0.w, c1.x, c1.y, c1.z, c1.w};

    float m = v8[0];
#pragma unroll
    for (int i = 1; i < 8; ++i) m = fmaxf(m, v8[i]);
#pragma unroll
    for (int off = 32; off > 0; off >>= 1) m = fmaxf(m, __shfl_down(m, off));
    int wid = t >> 6, lane = t & 63;
    if (lane == 0) red[wid] = m;
    __syncthreads();
    if (t == 0) bc = fmaxf(fmaxf(red[0], red[1]), fmaxf(red[2], red[3]));
    __syncthreads();
    m = bc;

    float p8[8];
    float s = 0.f;
#pragma unroll
    for (int i = 0; i < 8; ++i) { p8[i] = __expf(v8[i] - m); s += p8[i]; }
#pragma unroll
    for (int off = 32; off > 0; off >>= 1) s += __shfl_down(s, off);
    if (lane == 0) red[wid] = s;          // t0's reads of red (max) happened before prior barrier
    __syncthreads();
    if (t == 0) bc = red[0] + red[1] + red[2] + red[3];
    __syncthreads();
    float inv = 1.f / bc;

    float4 o0 = make_float4(p8[0] * inv, p8[1] * inv, p8[2] * inv, p8[3] * inv);
    float4 o1 = make_float4(p8[4] * inv, p8[5] * inv, p8[6] * inv, p8[7] * inv);
    float4* op = (float4*)(out + (size_t)b * MAXL);
    op[2 * t]     = o0;
    op[2 * t + 1] = o1;
}

// ---------------------------------------------------------------------------
// Fallback (only if ws is too small to hold w_eff + energies): fully fused,
// one block per batch row, w_eff recomputed per block into LDS.
// ---------------------------------------------------------------------------
__global__ __launch_bounds__(1024) void fused_kernel(const float* __restrict__ q,
                                                     const int*   __restrict__ lens,
                                                     const float* __restrict__ W,
                                                     const float* __restrict__ v,
                                                     float*       __restrict__ out) {
    __shared__ float weff_s[EMBED];
    __shared__ float eng[MAXL];
    __shared__ float red[16];
    __shared__ float bc;
    int b   = blockIdx.x;
    int len = lens[b];
    int t   = threadIdx.x;

    if (t < EMBED) {
        float acc = 0.f;
#pragma unroll 8
        for (int e = 0; e < EMBED; ++e) acc += W[(size_t)e * EMBED + t] * v[e];
        weff_s[t] = acc;
    }
    __syncthreads();

    int wid = t >> 6, lane = t & 63;
    const float4* wp = (const float4*)weff_s + lane * 2;
    float4 w0 = wp[0];
    float4 w1 = wp[1];
    for (int l = wid; l < MAXL; l += 16) {
        if (l >= len) {
            if (lane == 0) eng[l] = -INFINITY;
            continue;
        }
        const float4* qp = (const float4*)(q + (((size_t)b * MAXL + l) << 9)) + lane * 2;
        float4 a0 = qp[0];
        float4 a1 = qp[1];
        float p = a0.x * w0.x + a0.y * w0.y + a0.z * w0.z + a0.w * w0.w
                + a1.x * w1.x + a1.y * w1.y + a1.z * w1.z + a1.w * w1.w;
#pragma unroll
        for (int off = 32; off > 0; off >>= 1) p += __shfl_down(p, off);
        if (lane == 0) eng[l] = p;
    }
    __syncthreads();

    float e0 = eng[t], e1 = eng[t + 1024];
    float m = fmaxf(e0, e1);
#pragma unroll
    for (int off = 32; off > 0; off >>= 1) m = fmaxf(m, __shfl_down(m, off));
    if (lane == 0) red[wid] = m;
    __syncthreads();
    if (t == 0) {
        float mm = red[0];
        for (int i = 1; i < 16; ++i) mm = fmaxf(mm, red[i]);
        bc = mm;
    }
    __syncthreads();
    m = bc;

    float p0 = __expf(e0 - m), p1 = __expf(e1 - m);
    float s = p0 + p1;
#pragma unroll
    for (int off = 32; off > 0; off >>= 1) s += __shfl_down(s, off);
    if (lane == 0) red[wid] = s;
    __syncthreads();
    if (t == 0) {
        float ss = 0.f;
        for (int i = 0; i < 16; ++i) ss += red[i];
        bc = ss;
    }
    __syncthreads();
    float inv = 1.f / bc;
    out[(size_t)b * MAXL + t]        = p0 * inv;
    out[(size_t)b * MAXL + t + 1024] = p1 * inv;
}

extern "C" void kernel_launch(void* const* d_in, const int* in_sizes, int n_in,
                              void* d_out, int out_size, void* d_ws, size_t ws_size,
                              hipStream_t stream) {
    const float* q    = (const float*)d_in[0];   // [256, 2048, 512] f32
    const int*   lens = (const int*)d_in[1];     // [256] i32
    const float* W    = (const float*)d_in[2];   // [512, 512] f32
    // d_in[3] = lin_b — unused: softmax is invariant to the per-row constant b·v
    const float* v    = (const float*)d_in[4];   // [512] f32
    float* out = (float*)d_out;                  // [256, 2048] f32

    size_t need = (size_t)EMBED * sizeof(float) + (size_t)B2 * MAXL * sizeof(float);
    if (ws_size >= need) {
        float* weff     = (float*)d_ws;
        float* energies = weff + EMBED;
        hipMemsetAsync(weff, 0, EMBED * sizeof(float), stream);
        weff_kernel<<<16, 1024, 0, stream>>>(W, v, weff);
        energy_kernel<<<(B2 * MAXL) / 4, 256, 0, stream>>>(q, lens, weff, energies);
        softmax_kernel<<<B2, 256, 0, stream>>>(energies, out);
    } else {
        fused_kernel<<<B2, 1024, 0, stream>>>(q, lens, W, v, out);
    }
}